// Round 9
// baseline (113.293 us; speedup 1.0000x reference)
//
#include <hip/hip_runtime.h>

// Problem constants
#define NB      20000      // nodes per batch
#define BATCH   4
#define KNN     16
#define DD      128        // embedding dim
#define BM      64         // nodes per block
#define MW      136        // bf16 LDS row stride (mean / h / upd), padded from 128
#define NSLOT   157        // blocks per XCD slot (2*157*64 >= 20000 rows/batch)
#define GRID_MAIN (8*NSLOT)

#if defined(__has_builtin)
#if __has_builtin(__builtin_amdgcn_cvt_pk_fp8_f32) && __has_builtin(__builtin_amdgcn_cvt_pk_f32_fp8)
#define HAVE_FP8 1
#endif
#endif
#ifndef HAVE_FP8
#define HAVE_FP8 0
#endif

typedef __attribute__((ext_vector_type(8))) short          bf16x8;
typedef __attribute__((ext_vector_type(4))) float          f32x4;
typedef __attribute__((ext_vector_type(2))) float          f32x2;
typedef __attribute__((ext_vector_type(4))) int            i32x4;
typedef __attribute__((ext_vector_type(2))) int            i32x2;
typedef __attribute__((ext_vector_type(4))) unsigned short u16x4;
typedef __attribute__((ext_vector_type(8))) unsigned short u16x8;

__device__ __forceinline__ unsigned short f2bf(float f) {
    unsigned int u = __float_as_uint(f);
    u += 0x7fffu + ((u >> 16) & 1u);           // round-to-nearest-even
    return (unsigned short)(u >> 16);
}
__device__ __forceinline__ float bf2f(unsigned short u) {
    return __uint_as_float((unsigned int)u << 16);
}

// ---- weights prep: fold concat into W1a = W1x+W1d, W1b = W1m-W1d (transposed,
//      bf16 [col][k]); W2 -> W2T. 3*16384 elems, 192 blocks.
__global__ __launch_bounds__(256) void nr_prep_w(
    const float* __restrict__ W1, const float* __restrict__ W2,
    unsigned short* __restrict__ W1aT, unsigned short* __restrict__ W1bT,
    unsigned short* __restrict__ W2T)
{
    int tid = blockIdx.x * 256 + threadIdx.x;   // < 49152
    int col = (tid & 16383) / DD;
    int k   = (tid & 16383) % DD;
    if (tid < 16384) {
        W1aT[tid] = f2bf(W1[k * DD + col] + W1[(256 + k) * DD + col]);
    } else if (tid < 32768) {
        W1bT[tid - 16384] = f2bf(W1[(128 + k) * DD + col] - W1[(256 + k) * DD + col]);
    } else {
        W2T[tid - 32768] = f2bf(W2[k * DD + col]);
    }
}

// ---- emb prep (bf16 only): contiguous f32 -> bf16, 8 elems/thread
__global__ __launch_bounds__(256) void nr_prep_emb(
    const float* __restrict__ src, unsigned short* __restrict__ dst)
{
    long long i = ((long long)blockIdx.x * 256 + threadIdx.x) * 8;
    const float4* p = (const float4*)(src + i);
    float4 a = p[0], b = p[1];
    u16x8 o;
    o[0]=f2bf(a.x); o[1]=f2bf(a.y); o[2]=f2bf(a.z); o[3]=f2bf(a.w);
    o[4]=f2bf(b.x); o[5]=f2bf(b.y); o[6]=f2bf(b.z); o[7]=f2bf(b.w);
    *(u16x8*)(dst + i) = o;
}

#if HAVE_FP8
// ---- emb prep (both): f32 -> bf16 table AND fp8 e4m3 table, one pass
__global__ __launch_bounds__(256) void nr_prep_emb2(
    const float* __restrict__ src, unsigned short* __restrict__ dst,
    unsigned char* __restrict__ dstq)
{
    long long i = ((long long)blockIdx.x * 256 + threadIdx.x) * 8;
    const float4* p = (const float4*)(src + i);
    float4 a = p[0], b = p[1];
    u16x8 o;
    o[0]=f2bf(a.x); o[1]=f2bf(a.y); o[2]=f2bf(a.z); o[3]=f2bf(a.w);
    o[4]=f2bf(b.x); o[5]=f2bf(b.y); o[6]=f2bf(b.z); o[7]=f2bf(b.w);
    *(u16x8*)(dst + i) = o;
    int p0 = 0, p1 = 0;
    p0 = __builtin_amdgcn_cvt_pk_fp8_f32(a.x, a.y, p0, false);
    p0 = __builtin_amdgcn_cvt_pk_fp8_f32(a.z, a.w, p0, true);
    p1 = __builtin_amdgcn_cvt_pk_fp8_f32(b.x, b.y, p1, false);
    p1 = __builtin_amdgcn_cvt_pk_fp8_f32(b.z, b.w, p1, true);
    i32x2 q; q[0] = p0; q[1] = p1;
    *(i32x2*)(dstq + i) = q;
}
#endif

// MODE 0: fp8 gather (embq, 2.56 MB/batch -> L2-resident); x + residual from
//         bf16 embh (identical to MODE 1 outside the gather loop).
// MODE 1: bf16 gather from embh (R8 behavior).
// MODE 2: f32 gather fallback (no tables), x staged bf16 in extra LDS.
// Grid 8*NSLOT; blockIdx&7 = XCD (round-robin dispatch); XCD pair owns a batch.
template<int MODE>
__global__ __launch_bounds__(256, 4) void nr_main(
    const float* __restrict__ emb, const unsigned short* __restrict__ embh,
    const unsigned char* __restrict__ embq,
    const int* __restrict__ knn,
    const unsigned short* __restrict__ W1aT, const unsigned short* __restrict__ W1bT,
    const unsigned short* __restrict__ W2T,
    const float* __restrict__ b1, const float* __restrict__ b2,
    float* __restrict__ out)
{
    extern __shared__ unsigned short lds[];     // [64][MW] bf16: mean -> h -> upd
    unsigned short* ldsx = lds + BM * MW;       // MODE2 only: x bf16

    const int t     = threadIdx.x;
    const int xcd   = blockIdx.x & 7;
    const int slot  = blockIdx.x >> 3;          // 0..NSLOT-1
    const int batch = xcd >> 1;
    const int bib   = (xcd & 1) * NSLOT + slot; // 0..313
    const int m_base = batch * NB + bib * BM;
    const int mend   = batch * NB + NB;

    // -------- Phase 1: gather 16 neighbors, mean -> LDS (bf16)
    {
        const int node_local = t >> 2;          // 0..63
        const int dpart      = t & 3;           // 32 dims each
        int m = m_base + node_local;
        if (m >= mend) m = mend - 1;            // tail clamp (results discarded)

        int idx[KNN];
        const i32x4* kp4 = (const i32x4*)(knn + (long long)m * KNN);
        #pragma unroll
        for (int q = 0; q < 4; ++q) {
            i32x4 v = __builtin_nontemporal_load(kp4 + q);
            idx[4*q+0] = v[0]; idx[4*q+1] = v[1]; idx[4*q+2] = v[2]; idx[4*q+3] = v[3];
        }

        float sm[32];
        #pragma unroll
        for (int e = 0; e < 32; ++e) sm[e] = 0.f;

        if constexpr (MODE == 0) {
#if HAVE_FP8
            const unsigned char* qbase =
                embq + (long long)batch * NB * DD + dpart * 32;
            #pragma unroll 4
            for (int k = 0; k < KNN; ++k) {
                const i32x4* p = (const i32x4*)(qbase + (long long)idx[k] * DD);
                i32x4 A = p[0], B = p[1];       // 32 fp8 values
                #pragma unroll
                for (int w = 0; w < 4; ++w) {
                    f32x2 lo = __builtin_amdgcn_cvt_pk_f32_fp8(A[w], false);
                    f32x2 hi = __builtin_amdgcn_cvt_pk_f32_fp8(A[w], true);
                    sm[4*w+0] += lo[0]; sm[4*w+1] += lo[1];
                    sm[4*w+2] += hi[0]; sm[4*w+3] += hi[1];
                }
                #pragma unroll
                for (int w = 0; w < 4; ++w) {
                    f32x2 lo = __builtin_amdgcn_cvt_pk_f32_fp8(B[w], false);
                    f32x2 hi = __builtin_amdgcn_cvt_pk_f32_fp8(B[w], true);
                    sm[16+4*w+0] += lo[0]; sm[16+4*w+1] += lo[1];
                    sm[16+4*w+2] += hi[0]; sm[16+4*w+3] += hi[1];
                }
            }
#endif
        } else if constexpr (MODE == 1) {
            const unsigned short* nb_base =
                embh + (long long)batch * NB * DD + dpart * 32;
            #pragma unroll 4
            for (int k = 0; k < KNN; ++k) {
                const u16x8* np = (const u16x8*)(nb_base + (long long)idx[k] * DD);
                #pragma unroll
                for (int j = 0; j < 4; ++j) {
                    u16x8 v = np[j];
                    #pragma unroll
                    for (int e = 0; e < 8; ++e) sm[j*8+e] += bf2f(v[e]);
                }
            }
        } else {
            // f32 fallback: also stage x (bf16) in ldsx
            const float4* xp = (const float4*)(emb + (long long)m * DD + dpart * 32);
            unsigned short* xrow = ldsx + node_local * MW + dpart * 32;
            #pragma unroll
            for (int j = 0; j < 8; ++j) {
                float4 v = xp[j];
                xrow[j*4+0]=f2bf(v.x); xrow[j*4+1]=f2bf(v.y);
                xrow[j*4+2]=f2bf(v.z); xrow[j*4+3]=f2bf(v.w);
            }
            const long long bbase = (long long)batch * NB * DD + dpart * 32;
            #pragma unroll 4
            for (int k = 0; k < KNN; ++k) {
                const float4* np = (const float4*)(emb + bbase + (long long)idx[k] * DD);
                #pragma unroll
                for (int j = 0; j < 8; ++j) {
                    float4 v = np[j];
                    sm[j*4+0]+=v.x; sm[j*4+1]+=v.y; sm[j*4+2]+=v.z; sm[j*4+3]+=v.w;
                }
            }
        }

        unsigned short* mrow = lds + node_local * MW + dpart * 32;
        #pragma unroll
        for (int j = 0; j < 4; ++j) {
            u16x8 pm;
            #pragma unroll
            for (int e = 0; e < 8; ++e) pm[e] = f2bf(sm[j*8+e] * 0.0625f);
            *(u16x8*)(mrow + j*8) = pm;
        }
    }
    __syncthreads();

    // -------- Phase 2: GEMM1  h_pre = x@W1a + m@W1b  (K=128 each)
    const int wave = t >> 6;
    const int lane = t & 63;
    const int lrow = lane & 15;                 // A row / B col / D col
    const int lk   = lane >> 4;                 // 0..3

    const int row_g = m_base + wave * 16 + lrow;
    const int rowA  = (row_g < mend) ? row_g : (mend - 1);

    bf16x8 xf[4], mf[4];
    if constexpr (MODE != 2) {
        const unsigned short* xr = embh + (long long)rowA * DD + lk * 8;
        #pragma unroll
        for (int ks = 0; ks < 4; ++ks) xf[ks] = *(const bf16x8*)(xr + ks * 32);
    } else {
        const unsigned short* xr = ldsx + (wave * 16 + lrow) * MW + lk * 8;
        #pragma unroll
        for (int ks = 0; ks < 4; ++ks) xf[ks] = *(const bf16x8*)(xr + ks * 32);
    }
    {
        const unsigned short* mr = lds + (wave * 16 + lrow) * MW + lk * 8;
        #pragma unroll
        for (int ks = 0; ks < 4; ++ks) mf[ks] = *(const bf16x8*)(mr + ks * 32);
    }

    f32x4 acc[8];
    #pragma unroll
    for (int f = 0; f < 8; ++f) acc[f] = (f32x4){0.f, 0.f, 0.f, 0.f};

    #pragma unroll
    for (int ks = 0; ks < 4; ++ks) {
        #pragma unroll
        for (int f = 0; f < 8; ++f) {
            int col = f * 16 + lrow;
            bf16x8 bw = *(const bf16x8*)(W1aT + col * DD + ks * 32 + lk * 8);
            acc[f] = __builtin_amdgcn_mfma_f32_16x16x32_bf16(xf[ks], bw, acc[f], 0, 0, 0);
        }
    }
    #pragma unroll
    for (int ks = 0; ks < 4; ++ks) {
        #pragma unroll
        for (int f = 0; f < 8; ++f) {
            int col = f * 16 + lrow;
            bf16x8 bw = *(const bf16x8*)(W1bT + col * DD + ks * 32 + lk * 8);
            acc[f] = __builtin_amdgcn_mfma_f32_16x16x32_bf16(mf[ks], bw, acc[f], 0, 0, 0);
        }
    }
    __syncthreads();                            // mean reads done -> overwrite with h

    // epilogue 1: bias + exact GELU -> h (bf16) into SAME LDS region
    #pragma unroll
    for (int f = 0; f < 8; ++f) {
        int col = f * 16 + lrow;
        float bb = b1[col];
        #pragma unroll
        for (int r = 0; r < 4; ++r) {
            int row = wave * 16 + lk * 4 + r;
            float xg = acc[f][r] + bb;
            float hv = 0.5f * xg * (1.0f + erff(xg * 0.70710678118654752f));
            lds[row * MW + col] = f2bf(hv);
        }
    }
    __syncthreads();

    // -------- Phase 3: GEMM2  upd = h @ W2
    f32x4 acc2[8];
    #pragma unroll
    for (int f = 0; f < 8; ++f) acc2[f] = (f32x4){0.f, 0.f, 0.f, 0.f};
    {
        const unsigned short* abase = lds + (wave * 16 + lrow) * MW + lk * 8;
        #pragma unroll
        for (int ks = 0; ks < 4; ++ks) {
            bf16x8 af = *(const bf16x8*)(abase + ks * 32);
            #pragma unroll
            for (int f = 0; f < 8; ++f) {
                int col = f * 16 + lrow;
                bf16x8 bw = *(const bf16x8*)(W2T + col * DD + ks * 32 + lk * 8);
                acc2[f] = __builtin_amdgcn_mfma_f32_16x16x32_bf16(af, bw, acc2[f], 0, 0, 0);
            }
        }
    }
    __syncthreads();                            // h reads done -> overwrite with upd

    // epilogue 2a: bias -> upd (bf16) in SAME LDS region
    #pragma unroll
    for (int f = 0; f < 8; ++f) {
        int col = f * 16 + lrow;
        float bb = b2[col];
        #pragma unroll
        for (int r = 0; r < 4; ++r) {
            int row = wave * 16 + lk * 4 + r;
            lds[row * MW + col] = f2bf(acc2[f][r] + bb);
        }
    }
    __syncthreads();

    // epilogue 2b: residual + store; every wave store instruction covers
    // 1024 B contiguous (flat = i*1024 + t*4). Plain stores (full lines).
    {
        const long long gbase = (long long)m_base * DD;
        const int rows_valid  = mend - m_base;  // may be <64 (or <=0) at tail
        #pragma unroll
        for (int i = 0; i < 8; ++i) {
            int flat = i * 1024 + t * 4;        // f32 index in block's 64x128 tile
            int row  = flat >> 7;
            if (row < rows_valid) {
                u16x4 uv = *(const u16x4*)(lds + row * MW + (flat & 127));
                f32x4 ov;
                if constexpr (MODE != 2) {
                    u16x4 rv = *(const u16x4*)(embh + gbase + flat);
                    ov[0] = bf2f(rv[0]) + bf2f(uv[0]);
                    ov[1] = bf2f(rv[1]) + bf2f(uv[1]);
                    ov[2] = bf2f(rv[2]) + bf2f(uv[2]);
                    ov[3] = bf2f(rv[3]) + bf2f(uv[3]);
                } else {
                    f32x4 rv = *(const f32x4*)(emb + gbase + flat);
                    ov[0] = rv[0] + bf2f(uv[0]); ov[1] = rv[1] + bf2f(uv[1]);
                    ov[2] = rv[2] + bf2f(uv[2]); ov[3] = rv[3] + bf2f(uv[3]);
                }
                *(f32x4*)(out + gbase + flat) = ov;
            }
        }
    }
}

extern "C" void kernel_launch(void* const* d_in, const int* in_sizes, int n_in,
                              void* d_out, int out_size, void* d_ws, size_t ws_size,
                              hipStream_t stream) {
    const float* emb = (const float*)d_in[0];   // [B,N,D] f32
    const int*   knn = (const int*)  d_in[1];   // [B,N,K] i32
    const float* W1  = (const float*)d_in[2];   // [384,128]
    const float* b1  = (const float*)d_in[3];   // [128]
    const float* W2  = (const float*)d_in[4];   // [128,128]
    const float* b2  = (const float*)d_in[5];   // [128]
    float* out = (float*)d_out;

    unsigned short* W1aT = (unsigned short*)d_ws;           // 16384 u16
    unsigned short* W1bT = W1aT + 16384;                    // 16384 u16
    unsigned short* W2T  = W1bT + 16384;                    // 16384 u16
    unsigned short* embh = W2T  + 16384;                    // 10,240,000 u16
    unsigned char*  embq = (unsigned char*)(embh + 10240000); // 10,240,000 fp8

    const size_t NEED_BF16 = (size_t)(49152 + 10240000) * 2;            // ~20.6 MB
    const size_t NEED_FP8  = NEED_BF16 + (size_t)10240000;              // ~30.8 MB

    nr_prep_w<<<192, 256, 0, stream>>>(W1, W2, W1aT, W1bT, W2T);

#if HAVE_FP8
    if (ws_size >= NEED_FP8) {
        nr_prep_emb2<<<5000, 256, 0, stream>>>(emb, embh, embq);
        nr_main<0><<<GRID_MAIN, 256, BM * MW * 2, stream>>>(
            emb, embh, embq, knn, W1aT, W1bT, W2T, b1, b2, out);
        return;
    }
#endif
    if (ws_size >= NEED_BF16) {
        nr_prep_emb<<<5000, 256, 0, stream>>>(emb, embh);
        nr_main<1><<<GRID_MAIN, 256, BM * MW * 2, stream>>>(
            emb, embh, nullptr, knn, W1aT, W1bT, W2T, b1, b2, out);
    } else {
        nr_main<2><<<GRID_MAIN, 256, 2 * BM * MW * 2, stream>>>(
            emb, nullptr, nullptr, knn, W1aT, W1bT, W2T, b1, b2, out);
    }
}

// Round 10
// 112.649 us; speedup vs baseline: 1.0057x; 1.0057x over previous
//
#include <hip/hip_runtime.h>

// Problem constants
#define NB      20000      // nodes per batch
#define BATCH   4
#define KNN     16
#define DD      128        // embedding dim
#define BM      64         // nodes per block
#define MW      136        // bf16 LDS row stride, padded from 128
#define NSLOT   157        // blocks per XCD slot (2*157*64 >= 20000 rows/batch)
#define GRID_MAIN (8*NSLOT)

#if defined(__has_builtin)
#if __has_builtin(__builtin_amdgcn_cvt_pk_fp8_f32) && __has_builtin(__builtin_amdgcn_cvt_pk_f32_fp8)
#define HAVE_FP8 1
#endif
#endif
#ifndef HAVE_FP8
#define HAVE_FP8 0
#endif

typedef __attribute__((ext_vector_type(8))) short          bf16x8;
typedef __attribute__((ext_vector_type(4))) float          f32x4;
typedef __attribute__((ext_vector_type(2))) float          f32x2;
typedef __attribute__((ext_vector_type(4))) int            i32x4;
typedef __attribute__((ext_vector_type(2))) int            i32x2;
typedef __attribute__((ext_vector_type(4))) unsigned short u16x4;
typedef __attribute__((ext_vector_type(8))) unsigned short u16x8;

__device__ __forceinline__ unsigned short f2bf(float f) {
    unsigned int u = __float_as_uint(f);
    u += 0x7fffu + ((u >> 16) & 1u);           // round-to-nearest-even
    return (unsigned short)(u >> 16);
}
__device__ __forceinline__ float bf2f(unsigned short u) {
    return __uint_as_float((unsigned int)u << 16);
}

// ---- weights prep: fold concat into W1a = W1x+W1d, W1b = W1m-W1d (transposed,
//      bf16 [col][k]); W2 -> W2T. 3*16384 elems, 192 blocks.
__global__ __launch_bounds__(256) void nr_prep_w(
    const float* __restrict__ W1, const float* __restrict__ W2,
    unsigned short* __restrict__ W1aT, unsigned short* __restrict__ W1bT,
    unsigned short* __restrict__ W2T)
{
    int tid = blockIdx.x * 256 + threadIdx.x;   // < 49152
    int col = (tid & 16383) / DD;
    int k   = (tid & 16383) % DD;
    if (tid < 16384) {
        W1aT[tid] = f2bf(W1[k * DD + col] + W1[(256 + k) * DD + col]);
    } else if (tid < 32768) {
        W1bT[tid - 16384] = f2bf(W1[(128 + k) * DD + col] - W1[(256 + k) * DD + col]);
    } else {
        W2T[tid - 32768] = f2bf(W2[k * DD + col]);
    }
}

// ---- emb prep (bf16 tier): contiguous f32 -> bf16, 8 elems/thread
__global__ __launch_bounds__(256) void nr_prep_emb(
    const float* __restrict__ src, unsigned short* __restrict__ dst)
{
    long long i = ((long long)blockIdx.x * 256 + threadIdx.x) * 8;
    const float4* p = (const float4*)(src + i);
    float4 a = p[0], b = p[1];
    u16x8 o;
    o[0]=f2bf(a.x); o[1]=f2bf(a.y); o[2]=f2bf(a.z); o[3]=f2bf(a.w);
    o[4]=f2bf(b.x); o[5]=f2bf(b.y); o[6]=f2bf(b.z); o[7]=f2bf(b.w);
    *(u16x8*)(dst + i) = o;
}

#if HAVE_FP8
// ---- emb prep (fp8 tier): f32 -> fp8 e4m3 table only, 8 elems/thread
__global__ __launch_bounds__(256) void nr_prep_q(
    const float* __restrict__ src, unsigned char* __restrict__ dstq)
{
    long long i = ((long long)blockIdx.x * 256 + threadIdx.x) * 8;
    const float4* p = (const float4*)(src + i);
    float4 a = p[0], b = p[1];
    int p0 = 0, p1 = 0;
    p0 = __builtin_amdgcn_cvt_pk_fp8_f32(a.x, a.y, p0, false);
    p0 = __builtin_amdgcn_cvt_pk_fp8_f32(a.z, a.w, p0, true);
    p1 = __builtin_amdgcn_cvt_pk_fp8_f32(b.x, b.y, p1, false);
    p1 = __builtin_amdgcn_cvt_pk_fp8_f32(b.z, b.w, p1, true);
    i32x2 q; q[0] = p0; q[1] = p1;
    *(i32x2*)(dstq + i) = q;
}
#endif

// MODE 0: fp8 gather table (embq, 2.56 MB/batch -> L2-resident). x staged
//         coalesced from f32 emb into LDS; GEMM1 xf + residual from that LDS.
// MODE 1: bf16 table (embh) for gather + x + residual (R8-proven path).
// MODE 2: f32 gather fallback (no tables), x staged bf16 in extra LDS.
// Grid 8*NSLOT; blockIdx&7 = XCD (round-robin dispatch); XCD pair owns a batch.
template<int MODE>
__global__ __launch_bounds__(256, 4) void nr_main(
    const float* __restrict__ emb, const unsigned short* __restrict__ embh,
    const unsigned char* __restrict__ embq,
    const int* __restrict__ knn,
    const unsigned short* __restrict__ W1aT, const unsigned short* __restrict__ W1bT,
    const unsigned short* __restrict__ W2T,
    const float* __restrict__ b1, const float* __restrict__ b2,
    float* __restrict__ out)
{
    extern __shared__ unsigned short lds[];     // [64][MW] bf16: mean -> h -> upd
    unsigned short* ldsx = lds + BM * MW;       // MODE 0/2: x bf16 [64][MW]

    const int t     = threadIdx.x;
    const int xcd   = blockIdx.x & 7;
    const int slot  = blockIdx.x >> 3;          // 0..NSLOT-1
    const int batch = xcd >> 1;
    const int bib   = (xcd & 1) * NSLOT + slot; // 0..313
    const int m_base = batch * NB + bib * BM;
    const int mend   = batch * NB + NB;

    // -------- Phase 1: stage x (MODE 0/2), gather 16 neighbors, mean -> LDS
    {
        const int node_local = t >> 2;          // 0..63
        const int dpart      = t & 3;           // 32 dims each
        int m = m_base + node_local;
        if (m >= mend) m = mend - 1;            // tail clamp (results discarded)

        int idx[KNN];
        const i32x4* kp4 = (const i32x4*)(knn + (long long)m * KNN);
        #pragma unroll
        for (int q = 0; q < 4; ++q) {
            i32x4 v = __builtin_nontemporal_load(kp4 + q);
            idx[4*q+0] = v[0]; idx[4*q+1] = v[1]; idx[4*q+2] = v[2]; idx[4*q+3] = v[3];
        }

        if constexpr (MODE != 1) {
            // stage x: coalesced f32 -> bf16 -> ldsx
            const float4* xp = (const float4*)(emb + (long long)m * DD + dpart * 32);
            unsigned short* xrow = ldsx + node_local * MW + dpart * 32;
            #pragma unroll
            for (int j = 0; j < 8; ++j) {
                float4 v = xp[j];
                xrow[j*4+0]=f2bf(v.x); xrow[j*4+1]=f2bf(v.y);
                xrow[j*4+2]=f2bf(v.z); xrow[j*4+3]=f2bf(v.w);
            }
        }

        float sm[32];
        #pragma unroll
        for (int e = 0; e < 32; ++e) sm[e] = 0.f;

        if constexpr (MODE == 0) {
#if HAVE_FP8
            const unsigned char* qbase =
                embq + (long long)batch * NB * DD + dpart * 32;
            #pragma unroll 4
            for (int k = 0; k < KNN; ++k) {
                const i32x4* p = (const i32x4*)(qbase + (long long)idx[k] * DD);
                i32x4 A = p[0], B = p[1];       // 32 fp8 values
                #pragma unroll
                for (int w = 0; w < 4; ++w) {
                    f32x2 lo = __builtin_amdgcn_cvt_pk_f32_fp8(A[w], false);
                    f32x2 hi = __builtin_amdgcn_cvt_pk_f32_fp8(A[w], true);
                    sm[4*w+0] += lo[0]; sm[4*w+1] += lo[1];
                    sm[4*w+2] += hi[0]; sm[4*w+3] += hi[1];
                }
                #pragma unroll
                for (int w = 0; w < 4; ++w) {
                    f32x2 lo = __builtin_amdgcn_cvt_pk_f32_fp8(B[w], false);
                    f32x2 hi = __builtin_amdgcn_cvt_pk_f32_fp8(B[w], true);
                    sm[16+4*w+0] += lo[0]; sm[16+4*w+1] += lo[1];
                    sm[16+4*w+2] += hi[0]; sm[16+4*w+3] += hi[1];
                }
            }
#endif
        } else if constexpr (MODE == 1) {
            const unsigned short* nb_base =
                embh + (long long)batch * NB * DD + dpart * 32;
            #pragma unroll 4
            for (int k = 0; k < KNN; ++k) {
                const u16x8* np = (const u16x8*)(nb_base + (long long)idx[k] * DD);
                #pragma unroll
                for (int j = 0; j < 4; ++j) {
                    u16x8 v = np[j];
                    #pragma unroll
                    for (int e = 0; e < 8; ++e) sm[j*8+e] += bf2f(v[e]);
                }
            }
        } else {
            const long long bbase = (long long)batch * NB * DD + dpart * 32;
            #pragma unroll 4
            for (int k = 0; k < KNN; ++k) {
                const float4* np = (const float4*)(emb + bbase + (long long)idx[k] * DD);
                #pragma unroll
                for (int j = 0; j < 8; ++j) {
                    float4 v = np[j];
                    sm[j*4+0]+=v.x; sm[j*4+1]+=v.y; sm[j*4+2]+=v.z; sm[j*4+3]+=v.w;
                }
            }
        }

        unsigned short* mrow = lds + node_local * MW + dpart * 32;
        #pragma unroll
        for (int j = 0; j < 4; ++j) {
            u16x8 pm;
            #pragma unroll
            for (int e = 0; e < 8; ++e) pm[e] = f2bf(sm[j*8+e] * 0.0625f);
            *(u16x8*)(mrow + j*8) = pm;
        }
    }
    __syncthreads();

    // -------- Phase 2: GEMM1  h_pre = x@W1a + m@W1b  (K=128 each)
    const int wave = t >> 6;
    const int lane = t & 63;
    const int lrow = lane & 15;                 // A row / B col / D col
    const int lk   = lane >> 4;                 // 0..3

    const int row_g = m_base + wave * 16 + lrow;
    const int rowA  = (row_g < mend) ? row_g : (mend - 1);

    bf16x8 xf[4], mf[4];
    if constexpr (MODE == 1) {
        const unsigned short* xr = embh + (long long)rowA * DD + lk * 8;
        #pragma unroll
        for (int ks = 0; ks < 4; ++ks) xf[ks] = *(const bf16x8*)(xr + ks * 32);
    } else {
        const unsigned short* xr = ldsx + (wave * 16 + lrow) * MW + lk * 8;
        #pragma unroll
        for (int ks = 0; ks < 4; ++ks) xf[ks] = *(const bf16x8*)(xr + ks * 32);
    }
    {
        const unsigned short* mr = lds + (wave * 16 + lrow) * MW + lk * 8;
        #pragma unroll
        for (int ks = 0; ks < 4; ++ks) mf[ks] = *(const bf16x8*)(mr + ks * 32);
    }

    f32x4 acc[8];
    #pragma unroll
    for (int f = 0; f < 8; ++f) acc[f] = (f32x4){0.f, 0.f, 0.f, 0.f};

    #pragma unroll
    for (int ks = 0; ks < 4; ++ks) {
        #pragma unroll
        for (int f = 0; f < 8; ++f) {
            int col = f * 16 + lrow;
            bf16x8 bw = *(const bf16x8*)(W1aT + col * DD + ks * 32 + lk * 8);
            acc[f] = __builtin_amdgcn_mfma_f32_16x16x32_bf16(xf[ks], bw, acc[f], 0, 0, 0);
        }
    }
    #pragma unroll
    for (int ks = 0; ks < 4; ++ks) {
        #pragma unroll
        for (int f = 0; f < 8; ++f) {
            int col = f * 16 + lrow;
            bf16x8 bw = *(const bf16x8*)(W1bT + col * DD + ks * 32 + lk * 8);
            acc[f] = __builtin_amdgcn_mfma_f32_16x16x32_bf16(mf[ks], bw, acc[f], 0, 0, 0);
        }
    }
    __syncthreads();                            // mean reads done -> overwrite with h

    // epilogue 1: bias + exact GELU -> h (bf16) into SAME LDS region
    #pragma unroll
    for (int f = 0; f < 8; ++f) {
        int col = f * 16 + lrow;
        float bb = b1[col];
        #pragma unroll
        for (int r = 0; r < 4; ++r) {
            int row = wave * 16 + lk * 4 + r;
            float xg = acc[f][r] + bb;
            float hv = 0.5f * xg * (1.0f + erff(xg * 0.70710678118654752f));
            lds[row * MW + col] = f2bf(hv);
        }
    }
    __syncthreads();

    // -------- Phase 3: GEMM2  upd = h @ W2
    f32x4 acc2[8];
    #pragma unroll
    for (int f = 0; f < 8; ++f) acc2[f] = (f32x4){0.f, 0.f, 0.f, 0.f};
    {
        const unsigned short* abase = lds + (wave * 16 + lrow) * MW + lk * 8;
        #pragma unroll
        for (int ks = 0; ks < 4; ++ks) {
            bf16x8 af = *(const bf16x8*)(abase + ks * 32);
            #pragma unroll
            for (int f = 0; f < 8; ++f) {
                int col = f * 16 + lrow;
                bf16x8 bw = *(const bf16x8*)(W2T + col * DD + ks * 32 + lk * 8);
                acc2[f] = __builtin_amdgcn_mfma_f32_16x16x32_bf16(af, bw, acc2[f], 0, 0, 0);
            }
        }
    }
    __syncthreads();                            // h reads done -> overwrite with upd

    // epilogue 2a: bias -> upd (bf16) in SAME LDS region
    #pragma unroll
    for (int f = 0; f < 8; ++f) {
        int col = f * 16 + lrow;
        float bb = b2[col];
        #pragma unroll
        for (int r = 0; r < 4; ++r) {
            int row = wave * 16 + lk * 4 + r;
            lds[row * MW + col] = f2bf(acc2[f][r] + bb);
        }
    }
    __syncthreads();

    // epilogue 2b: residual + store; every wave store instruction covers
    // 1024 B contiguous (flat = i*1024 + t*4). Plain stores (full lines).
    {
        const long long gbase = (long long)m_base * DD;
        const int rows_valid  = mend - m_base;  // may be <64 at tail
        #pragma unroll
        for (int i = 0; i < 8; ++i) {
            int flat = i * 1024 + t * 4;        // f32 index in block's 64x128 tile
            int row  = flat >> 7;
            if (row < rows_valid) {
                u16x4 uv = *(const u16x4*)(lds + row * MW + (flat & 127));
                f32x4 ov;
                if constexpr (MODE == 1) {
                    u16x4 rv = *(const u16x4*)(embh + gbase + flat);
                    ov[0] = bf2f(rv[0]) + bf2f(uv[0]);
                    ov[1] = bf2f(rv[1]) + bf2f(uv[1]);
                    ov[2] = bf2f(rv[2]) + bf2f(uv[2]);
                    ov[3] = bf2f(rv[3]) + bf2f(uv[3]);
                } else {
                    u16x4 rv = *(const u16x4*)(ldsx + row * MW + (flat & 127));
                    ov[0] = bf2f(rv[0]) + bf2f(uv[0]);
                    ov[1] = bf2f(rv[1]) + bf2f(uv[1]);
                    ov[2] = bf2f(rv[2]) + bf2f(uv[2]);
                    ov[3] = bf2f(rv[3]) + bf2f(uv[3]);
                }
                *(f32x4*)(out + gbase + flat) = ov;
            }
        }
    }
}

extern "C" void kernel_launch(void* const* d_in, const int* in_sizes, int n_in,
                              void* d_out, int out_size, void* d_ws, size_t ws_size,
                              hipStream_t stream) {
    const float* emb = (const float*)d_in[0];   // [B,N,D] f32
    const int*   knn = (const int*)  d_in[1];   // [B,N,K] i32
    const float* W1  = (const float*)d_in[2];   // [384,128]
    const float* b1  = (const float*)d_in[3];   // [128]
    const float* W2  = (const float*)d_in[4];   // [128,128]
    const float* b2  = (const float*)d_in[5];   // [128]
    float* out = (float*)d_out;

    unsigned short* W1aT = (unsigned short*)d_ws;           // 16384 u16
    unsigned short* W1bT = W1aT + 16384;                    // 16384 u16
    unsigned short* W2T  = W1bT + 16384;                    // 16384 u16
    unsigned short* embh = W2T  + 16384;                    // bf16 tier table
    unsigned char*  embq = (unsigned char*)(W2T + 16384);   // fp8 tier table

    const size_t NEED_FP8  = (size_t)49152 * 2 + 10240000;         // ~10.3 MB
    const size_t NEED_BF16 = (size_t)(49152 + 10240000) * 2;       // ~20.6 MB

    nr_prep_w<<<192, 256, 0, stream>>>(W1, W2, W1aT, W1bT, W2T);

#if HAVE_FP8
    if (ws_size >= NEED_FP8) {
        nr_prep_q<<<5000, 256, 0, stream>>>(emb, embq);     // 5000*2048 = 10.24M
        nr_main<0><<<GRID_MAIN, 256, 2 * BM * MW * 2, stream>>>(
            emb, nullptr, embq, knn, W1aT, W1bT, W2T, b1, b2, out);
        return;
    }
#endif
    if (ws_size >= NEED_BF16) {
        nr_prep_emb<<<5000, 256, 0, stream>>>(emb, embh);
        nr_main<1><<<GRID_MAIN, 256, BM * MW * 2, stream>>>(
            emb, embh, nullptr, knn, W1aT, W1bT, W2T, b1, b2, out);
    } else {
        nr_main<2><<<GRID_MAIN, 256, 2 * BM * MW * 2, stream>>>(
            emb, nullptr, nullptr, knn, W1aT, W1bT, W2T, b1, b2, out);
    }
}

// Round 11
// 96.908 us; speedup vs baseline: 1.1691x; 1.1624x over previous
//
#include <hip/hip_runtime.h>

// Problem constants
#define NB      20000      // nodes per batch
#define BATCH   4
#define KNN     16
#define DD      128        // embedding dim
#define BM      32         // nodes per block (32 -> 2504 blocks, ~9.8/CU)
#define MW      136        // bf16 LDS row stride, padded from 128
#define NSLOT   313        // blocks per XCD half-batch: 313*32 = 10016 rows
#define GRID_MAIN (8*NSLOT)

// Device-pass-only builtin detection (host pass sees 0 -> manual fallback,
// which is fine: __global__/__device__ bodies are only codegen'd for device).
#if defined(__has_builtin)
#if __has_builtin(__builtin_amdgcn_cvt_pk_f32_fp8)
#define FP8_DEC_BUILTIN 1
#endif
#endif

typedef __attribute__((ext_vector_type(8))) short          bf16x8;
typedef __attribute__((ext_vector_type(4))) float          f32x4;
typedef __attribute__((ext_vector_type(2))) float          f32x2;
typedef __attribute__((ext_vector_type(4))) int            i32x4;
typedef __attribute__((ext_vector_type(2))) int            i32x2;
typedef __attribute__((ext_vector_type(4))) unsigned short u16x4;
typedef __attribute__((ext_vector_type(8))) unsigned short u16x8;

__device__ __forceinline__ unsigned short f2bf(float f) {
    unsigned int u = __float_as_uint(f);
    u += 0x7fffu + ((u >> 16) & 1u);           // round-to-nearest-even
    return (unsigned short)(u >> 16);
}
__device__ __forceinline__ float bf2f(unsigned short u) {
    return __uint_as_float((unsigned int)u << 16);
}

// ---- e4m3fn encode (manual, RNE, clamp 448, denormals) — used by prep only
__device__ __forceinline__ unsigned int f32_to_e4m3(float x) {
    unsigned int u   = __float_as_uint(x);
    unsigned int sgn = (u >> 24) & 0x80u;
    float ax = fabsf(x);
    unsigned int em;
    if (ax < 0.015625f) {                       // denormal: m * 2^-9
        em = (unsigned int)rintf(ax * 512.0f);  // 0..8 (8 == 2^-6 normal, ok)
    } else {
        unsigned int mag = __float_as_uint(fminf(ax, 448.0f));
        em = ((mag + 0x7FFFFu + ((mag >> 20) & 1u)) >> 20) - 0x3C0u;
    }
    return sgn | em;
}

// ---- e4m3fn decode 4 bytes of w, accumulate into s[0..3]
__device__ __forceinline__ void acc4_fp8(unsigned int w, float* s) {
#if defined(FP8_DEC_BUILTIN)
    f32x2 lo = __builtin_amdgcn_cvt_pk_f32_fp8((int)w, false);
    f32x2 hi = __builtin_amdgcn_cvt_pk_f32_fp8((int)w, true);
    s[0] += lo[0]; s[1] += lo[1]; s[2] += hi[0]; s[3] += hi[1];
#else
    #pragma unroll
    for (int j = 0; j < 4; ++j) {
        unsigned int b  = (w >> (8 * j)) & 0xFFu;
        unsigned int em = b & 0x7Fu;
        float f  = __uint_as_float((em << 20) + 0x3C000000u);   // normal
        float fd = (float)em * 0.001953125f;                    // denorm m*2^-9
        f = (em < 8u) ? fd : f;
        f = __uint_as_float(__float_as_uint(f) | ((b & 0x80u) << 24));
        s[j] += f;
    }
#endif
}

// ---- weights prep: fold concat into W1a = W1x+W1d, W1b = W1m-W1d (transposed,
//      bf16 [col][k]); W2 -> W2T. 3*16384 elems, 192 blocks.
__global__ __launch_bounds__(256) void nr_prep_w(
    const float* __restrict__ W1, const float* __restrict__ W2,
    unsigned short* __restrict__ W1aT, unsigned short* __restrict__ W1bT,
    unsigned short* __restrict__ W2T)
{
    int tid = blockIdx.x * 256 + threadIdx.x;   // < 49152
    int col = (tid & 16383) / DD;
    int k   = (tid & 16383) % DD;
    if (tid < 16384) {
        W1aT[tid] = f2bf(W1[k * DD + col] + W1[(256 + k) * DD + col]);
    } else if (tid < 32768) {
        W1bT[tid - 16384] = f2bf(W1[(128 + k) * DD + col] - W1[(256 + k) * DD + col]);
    } else {
        W2T[tid - 32768] = f2bf(W2[k * DD + col]);
    }
}

// ---- emb prep: f32 -> fp8 e4m3 table, 8 elems/thread, 5000 blocks
__global__ __launch_bounds__(256) void nr_prep_q(
    const float* __restrict__ src, unsigned char* __restrict__ dstq)
{
    long long i = ((long long)blockIdx.x * 256 + threadIdx.x) * 8;
    const float4* p = (const float4*)(src + i);
    float4 a = p[0], b = p[1];
    unsigned int w0 = f32_to_e4m3(a.x) | (f32_to_e4m3(a.y) << 8) |
                      (f32_to_e4m3(a.z) << 16) | (f32_to_e4m3(a.w) << 24);
    unsigned int w1 = f32_to_e4m3(b.x) | (f32_to_e4m3(b.y) << 8) |
                      (f32_to_e4m3(b.z) << 16) | (f32_to_e4m3(b.w) << 24);
    i32x2 q; q[0] = (int)w0; q[1] = (int)w1;
    *(i32x2*)(dstq + i) = q;
}

// MODE 0: fp8 gather table (embq, 2.56 MB/batch -> L2-resident via XCD-batch
//         affinity). x staged once from f32 emb (nt) into LDS; GEMM1 xf and
//         the residual both read that LDS copy.
// MODE 2: f32 gather fallback (no table), x staged the same way.
// Grid 8*NSLOT; blockIdx&7 = XCD (round-robin dispatch); XCD pair owns a batch.
template<int MODE>
__global__ __launch_bounds__(256, 4) void nr_main(
    const float* __restrict__ emb, const unsigned char* __restrict__ embq,
    const int* __restrict__ knn,
    const unsigned short* __restrict__ W1aT, const unsigned short* __restrict__ W1bT,
    const unsigned short* __restrict__ W2T,
    const float* __restrict__ b1, const float* __restrict__ b2,
    float* __restrict__ out)
{
    extern __shared__ unsigned short lds[];     // [32][MW] bf16: mean -> h -> upd
    unsigned short* ldsx = lds + BM * MW;       // [32][MW] bf16: x

    const int t     = threadIdx.x;
    const int xcd   = blockIdx.x & 7;
    const int slot  = blockIdx.x >> 3;          // 0..NSLOT-1
    const int batch = xcd >> 1;
    const int bib   = (xcd & 1) * NSLOT + slot; // 0..625
    const int m_base = batch * NB + bib * BM;
    const int mend   = batch * NB + NB;

    // -------- Phase 1: stage x, gather 16 neighbors, mean -> LDS
    {
        const int node_local = t >> 3;          // 0..31
        const int dpart      = t & 7;           // 16 dims each
        int m = m_base + node_local;
        if (m >= mend) m = mend - 1;            // tail clamp (results discarded)

        int idx[KNN];
        const i32x4* kp4 = (const i32x4*)(knn + (long long)m * KNN);
        #pragma unroll
        for (int q = 0; q < 4; ++q) {
            i32x4 v = __builtin_nontemporal_load(kp4 + q);
            idx[4*q+0] = v[0]; idx[4*q+1] = v[1]; idx[4*q+2] = v[2]; idx[4*q+3] = v[3];
        }

        // stage x: coalesced f32 -> bf16 -> ldsx (nt: read exactly once)
        {
            const f32x4* xp = (const f32x4*)(emb + (long long)m * DD + dpart * 16);
            unsigned short* xrow = ldsx + node_local * MW + dpart * 16;
            #pragma unroll
            for (int j = 0; j < 4; ++j) {
                f32x4 v = __builtin_nontemporal_load(xp + j);
                u16x4 o;
                o[0]=f2bf(v[0]); o[1]=f2bf(v[1]); o[2]=f2bf(v[2]); o[3]=f2bf(v[3]);
                *(u16x4*)(xrow + j*4) = o;
            }
        }

        float sm[16];
        #pragma unroll
        for (int e = 0; e < 16; ++e) sm[e] = 0.f;

        if constexpr (MODE == 0) {
            const unsigned char* qbase =
                embq + (long long)batch * NB * DD + dpart * 16;
            #pragma unroll 8
            for (int k = 0; k < KNN; ++k) {
                i32x4 v = *(const i32x4*)(qbase + (long long)idx[k] * DD);
                acc4_fp8((unsigned int)v[0], sm + 0);
                acc4_fp8((unsigned int)v[1], sm + 4);
                acc4_fp8((unsigned int)v[2], sm + 8);
                acc4_fp8((unsigned int)v[3], sm + 12);
            }
        } else {
            const long long bbase = (long long)batch * NB * DD + dpart * 16;
            #pragma unroll 4
            for (int k = 0; k < KNN; ++k) {
                const f32x4* np = (const f32x4*)(emb + bbase + (long long)idx[k] * DD);
                #pragma unroll
                for (int j = 0; j < 4; ++j) {
                    f32x4 v = np[j];
                    sm[j*4+0]+=v[0]; sm[j*4+1]+=v[1]; sm[j*4+2]+=v[2]; sm[j*4+3]+=v[3];
                }
            }
        }

        unsigned short* mrow = lds + node_local * MW + dpart * 16;
        #pragma unroll
        for (int j = 0; j < 2; ++j) {
            u16x8 pm;
            #pragma unroll
            for (int e = 0; e < 8; ++e) pm[e] = f2bf(sm[j*8+e] * 0.0625f);
            *(u16x8*)(mrow + j*8) = pm;
        }
    }
    __syncthreads();

    // -------- Phase 2: GEMM1  h_pre = x@W1a + m@W1b  (K=128 each)
    // 4 waves: wr = wave&1 (16-row half), wc = wave>>1 (64-col half)
    const int wave = t >> 6;
    const int lane = t & 63;
    const int lrow = lane & 15;
    const int lk   = lane >> 4;                 // 0..3
    const int wr   = wave & 1;
    const int wc   = wave >> 1;
    const int Arow = wr * 16 + lrow;

    bf16x8 xf[4], mf[4];
    {
        const unsigned short* xr = ldsx + Arow * MW + lk * 8;
        const unsigned short* mr = lds  + Arow * MW + lk * 8;
        #pragma unroll
        for (int ks = 0; ks < 4; ++ks) {
            xf[ks] = *(const bf16x8*)(xr + ks * 32);
            mf[ks] = *(const bf16x8*)(mr + ks * 32);
        }
    }

    f32x4 acc[4];
    #pragma unroll
    for (int f = 0; f < 4; ++f) acc[f] = (f32x4){0.f, 0.f, 0.f, 0.f};

    #pragma unroll
    for (int ks = 0; ks < 4; ++ks) {
        #pragma unroll
        for (int f = 0; f < 4; ++f) {
            int col = wc * 64 + f * 16 + lrow;
            bf16x8 bw = *(const bf16x8*)(W1aT + col * DD + ks * 32 + lk * 8);
            acc[f] = __builtin_amdgcn_mfma_f32_16x16x32_bf16(xf[ks], bw, acc[f], 0, 0, 0);
        }
    }
    #pragma unroll
    for (int ks = 0; ks < 4; ++ks) {
        #pragma unroll
        for (int f = 0; f < 4; ++f) {
            int col = wc * 64 + f * 16 + lrow;
            bf16x8 bw = *(const bf16x8*)(W1bT + col * DD + ks * 32 + lk * 8);
            acc[f] = __builtin_amdgcn_mfma_f32_16x16x32_bf16(mf[ks], bw, acc[f], 0, 0, 0);
        }
    }
    __syncthreads();                            // mean reads done -> overwrite with h

    // epilogue 1: bias + exact GELU -> h (bf16) into SAME LDS region
    #pragma unroll
    for (int f = 0; f < 4; ++f) {
        int col = wc * 64 + f * 16 + lrow;
        float bb = b1[col];
        #pragma unroll
        for (int r = 0; r < 4; ++r) {
            int row = wr * 16 + lk * 4 + r;
            float xg = acc[f][r] + bb;
            float hv = 0.5f * xg * (1.0f + erff(xg * 0.70710678118654752f));
            lds[row * MW + col] = f2bf(hv);
        }
    }
    __syncthreads();

    // -------- Phase 3: GEMM2  upd = h @ W2
    f32x4 acc2[4];
    #pragma unroll
    for (int f = 0; f < 4; ++f) acc2[f] = (f32x4){0.f, 0.f, 0.f, 0.f};
    {
        const unsigned short* abase = lds + Arow * MW + lk * 8;
        #pragma unroll
        for (int ks = 0; ks < 4; ++ks) {
            bf16x8 af = *(const bf16x8*)(abase + ks * 32);
            #pragma unroll
            for (int f = 0; f < 4; ++f) {
                int col = wc * 64 + f * 16 + lrow;
                bf16x8 bw = *(const bf16x8*)(W2T + col * DD + ks * 32 + lk * 8);
                acc2[f] = __builtin_amdgcn_mfma_f32_16x16x32_bf16(af, bw, acc2[f], 0, 0, 0);
            }
        }
    }
    __syncthreads();                            // h reads done -> overwrite with upd

    // epilogue 2a: bias -> upd (bf16) in SAME LDS region
    #pragma unroll
    for (int f = 0; f < 4; ++f) {
        int col = wc * 64 + f * 16 + lrow;
        float bb = b2[col];
        #pragma unroll
        for (int r = 0; r < 4; ++r) {
            int row = wr * 16 + lk * 4 + r;
            lds[row * MW + col] = f2bf(acc2[f][r] + bb);
        }
    }
    __syncthreads();

    // epilogue 2b: residual (from staged x) + store; each wave store covers
    // 1024 B contiguous (flat = i*1024 + t*4). Plain stores (full lines).
    {
        const long long gbase = (long long)m_base * DD;
        const int rows_valid  = mend - m_base;  // 0 for the one dead tail block
        #pragma unroll
        for (int i = 0; i < 4; ++i) {
            int flat = i * 1024 + t * 4;        // f32 index in block's 32x128 tile
            int row  = flat >> 7;
            if (row < rows_valid) {
                u16x4 uv = *(const u16x4*)(lds  + row * MW + (flat & 127));
                u16x4 rv = *(const u16x4*)(ldsx + row * MW + (flat & 127));
                f32x4 ov;
                ov[0] = bf2f(rv[0]) + bf2f(uv[0]);
                ov[1] = bf2f(rv[1]) + bf2f(uv[1]);
                ov[2] = bf2f(rv[2]) + bf2f(uv[2]);
                ov[3] = bf2f(rv[3]) + bf2f(uv[3]);
                *(f32x4*)(out + gbase + flat) = ov;
            }
        }
    }
}

extern "C" void kernel_launch(void* const* d_in, const int* in_sizes, int n_in,
                              void* d_out, int out_size, void* d_ws, size_t ws_size,
                              hipStream_t stream) {
    const float* emb = (const float*)d_in[0];   // [B,N,D] f32
    const int*   knn = (const int*)  d_in[1];   // [B,N,K] i32
    const float* W1  = (const float*)d_in[2];   // [384,128]
    const float* b1  = (const float*)d_in[3];   // [128]
    const float* W2  = (const float*)d_in[4];   // [128,128]
    const float* b2  = (const float*)d_in[5];   // [128]
    float* out = (float*)d_out;

    unsigned short* W1aT = (unsigned short*)d_ws;           // 16384 u16
    unsigned short* W1bT = W1aT + 16384;                    // 16384 u16
    unsigned short* W2T  = W1bT + 16384;                    // 16384 u16
    unsigned char*  embq = (unsigned char*)(W2T + 16384);   // 10,240,000 fp8

    const size_t NEED_FP8 = (size_t)49152 * 2 + 10240000;   // ~10.3 MB

    nr_prep_w<<<192, 256, 0, stream>>>(W1, W2, W1aT, W1bT, W2T);

    if (ws_size >= NEED_FP8) {
        nr_prep_q<<<5000, 256, 0, stream>>>(emb, embq);     // 5000*2048 = 10.24M
        nr_main<0><<<GRID_MAIN, 256, 2 * BM * MW * 2, stream>>>(
            emb, embq, knn, W1aT, W1bT, W2T, b1, b2, out);
    } else {
        nr_main<2><<<GRID_MAIN, 256, 2 * BM * MW * 2, stream>>>(
            emb, nullptr, knn, W1aT, W1bT, W2T, b1, b2, out);
    }
}